// Round 2
// baseline (330.370 us; speedup 1.0000x reference)
//
#include <hip/hip_runtime.h>
#include <hip/hip_bf16.h>
#include <math.h>

// Cosine attention, n=8, L=S=2048, d=v=64.
// out0 = softmax((q^·k^T)/8) @ V  [8,2048,64]; out1 = softmax scores [8,2048,2048]
// Key fact: |score| <= 1/8 (unit vectors) -> exp in [0.88,1.13] -> no max needed.
// Normalization is linear -> PV runs on unnormalized exp, scaled at the end.
// Mask arrives as int32 (harness materializes bool as int) — NOT bytes.

typedef __bf16 bf16x8 __attribute__((ext_vector_type(8)));
typedef __bf16 bf16x4 __attribute__((ext_vector_type(4)));
typedef float f32x4 __attribute__((ext_vector_type(4)));

#define NB 8
#define LL 2048
#define SS 2048
#define DD 64

// ---- prep 1: L2-normalize Q (fold 1/8) and K rows, cast to bf16 ----
// one wave per row; 4 rows per 256-thread block; rows 0..16383 = Q, 16384.. = K
__global__ __launch_bounds__(256) void prep_norm(const float* __restrict__ q,
                                                 const float* __restrict__ k,
                                                 __bf16* __restrict__ Qb,
                                                 __bf16* __restrict__ Kb) {
  int w = threadIdx.x >> 6, lane = threadIdx.x & 63;
  int r = blockIdx.x * 4 + w;
  const float* src;
  __bf16* dst;
  float extra;
  if (r < NB * LL) {
    src = q + (size_t)r * DD;
    dst = Qb + (size_t)r * DD;
    extra = 0.125f;  // fold 1/sqrt(64) into Q
  } else {
    int rk = r - NB * LL;
    src = k + (size_t)rk * DD;
    dst = Kb + (size_t)rk * DD;
    extra = 1.0f;
  }
  float x = src[lane];
  float ss = x * x;
  ss += __shfl_xor(ss, 1);
  ss += __shfl_xor(ss, 2);
  ss += __shfl_xor(ss, 4);
  ss += __shfl_xor(ss, 8);
  ss += __shfl_xor(ss, 16);
  ss += __shfl_xor(ss, 32);
  float nrm = sqrtf(ss);
  float sc = extra / fmaxf(nrm, 1e-12f);
  dst[lane] = (__bf16)(x * sc);
}

// ---- prep 2: V [n][s][v] f32 -> Vt [n][v][s] bf16 (64x64 LDS tiles) ----
__global__ __launch_bounds__(256) void prep_vt(const float* __restrict__ v,
                                               __bf16* __restrict__ Vt) {
  __shared__ __bf16 tile[64][72];
  int n = blockIdx.y;
  int s0 = blockIdx.x * 64;
  int t = threadIdx.x;
#pragma unroll
  for (int it = 0; it < 4; ++it) {
    int idx = t + it * 256;
    int s = idx >> 4, c = idx & 15;
    float4 f = *(const float4*)(v + ((size_t)(n * SS + s0 + s)) * DD + c * 4);
    tile[s][c * 4 + 0] = (__bf16)f.x;
    tile[s][c * 4 + 1] = (__bf16)f.y;
    tile[s][c * 4 + 2] = (__bf16)f.z;
    tile[s][c * 4 + 3] = (__bf16)f.w;
  }
  __syncthreads();
#pragma unroll
  for (int it = 0; it < 4; ++it) {
    int idx = t + it * 256;
    int vv = idx >> 4, c = idx & 15;
    bf16x4 o;
    o[0] = tile[c * 4 + 0][vv];
    o[1] = tile[c * 4 + 1][vv];
    o[2] = tile[c * 4 + 2][vv];
    o[3] = tile[c * 4 + 3][vv];
    *(bf16x4*)(Vt + ((size_t)(n * DD + vv)) * SS + s0 + c * 4) = o;
  }
}

// ---- main: 16 L-rows per block, 4 waves, stream S in 64-col chunks ----
// Pass A: QK mfma -> exp -> rowsum + (LDS roundtrip) PV mfma with Vt frags.
// Reduce rowsums; write out_value = acc_o/rowsum.
// Pass B: recompute QK -> exp -> *inv -> store score (only HBM write of P).
__global__ __launch_bounds__(256, 4) void attn_main(const __bf16* __restrict__ Qb,
                                                    const __bf16* __restrict__ Kb,
                                                    const __bf16* __restrict__ Vt,
                                                    const int* __restrict__ mask,
                                                    float* __restrict__ out_val,
                                                    float* __restrict__ out_score) {
  __shared__ __bf16 e_lds[2][16][72];   // chunk of exp scores, C/D->A layout bounce
  __shared__ float rs_lds[4][16];       // per-wave row-sum partials

  const int n = blockIdx.y;
  const int l0 = blockIdx.x * 16;
  const int t = threadIdx.x;
  const int w = t >> 6;        // wave 0..3 -> owns s-cols [16w,16w+16) of each chunk / v-cols [16w,16w+16)
  const int lane = t & 63;
  const int m16 = lane & 15;   // MFMA A row / B col / C col
  const int quad = lane >> 4;  // C/D row group

  // Q A-frags: A[m=lane&15][k=quad*8+j], two k-steps of 32
  const __bf16* qrow = Qb + ((size_t)(n * LL + l0 + m16)) * DD;
  bf16x8 aq0 = *(const bf16x8*)(qrow + quad * 8);
  bf16x8 aq1 = *(const bf16x8*)(qrow + 32 + quad * 8);

  const __bf16* kbase = Kb + (size_t)n * SS * DD;
  const __bf16* vbase = Vt + (size_t)n * DD * SS;
  const size_t mrow_base = ((size_t)(n * LL + l0)) * SS;

  f32x4 acc_o = {0.f, 0.f, 0.f, 0.f};
  float rsum[4] = {0.f, 0.f, 0.f, 0.f};

  for (int c = 0; c < SS / 64; ++c) {
    const int sc = c * 64;
    const int scol = sc + w * 16 + m16;
    // --- QK^T for this wave's 16 s-cols ---
    const __bf16* krow = kbase + (size_t)scol * DD;
    bf16x8 b0 = *(const bf16x8*)(krow + quad * 8);
    bf16x8 b1 = *(const bf16x8*)(krow + 32 + quad * 8);
    f32x4 acc = {0.f, 0.f, 0.f, 0.f};
    acc = __builtin_amdgcn_mfma_f32_16x16x32_bf16(aq0, b0, acc, 0, 0, 0);
    acc = __builtin_amdgcn_mfma_f32_16x16x32_bf16(aq1, b1, acc, 0, 0, 0);
    // --- mask, exp, rowsum, stash bf16 e into LDS (C/D layout rows) ---
#pragma unroll
    for (int r = 0; r < 4; ++r) {
      int row = quad * 4 + r;
      int mk = mask[mrow_base + (size_t)row * SS + scol];
      float e = mk ? __expf(acc[r]) : 0.0f;
      rsum[r] += e;
      e_lds[c & 1][row][w * 16 + m16] = (__bf16)e;
    }
    __syncthreads();
    // --- PV: acc_o += E_chunk @ V_chunk ; A from LDS, B direct from global Vt ---
#pragma unroll
    for (int ks = 0; ks < 2; ++ks) {
      bf16x8 ae = *(const bf16x8*)(&e_lds[c & 1][m16][ks * 32 + quad * 8]);
      bf16x8 bv = *(const bf16x8*)(vbase + (size_t)(16 * w + m16) * SS + sc + ks * 32 + quad * 8);
      acc_o = __builtin_amdgcn_mfma_f32_16x16x32_bf16(ae, bv, acc_o, 0, 0, 0);
    }
    // no second barrier: buffer (c&1) is next written at chunk c+2, which is
    // after barrier c+1, which is after all reads of chunk c. (std dbuf proof)
  }

  // --- rowsum reduce: 16 lanes (cols) via shfl, then 4 waves via LDS ---
#pragma unroll
  for (int r = 0; r < 4; ++r) {
    float s = rsum[r];
    s += __shfl_xor(s, 1);
    s += __shfl_xor(s, 2);
    s += __shfl_xor(s, 4);
    s += __shfl_xor(s, 8);
    rsum[r] = s;
  }
  if (m16 == 0) {
#pragma unroll
    for (int r = 0; r < 4; ++r) rs_lds[w][quad * 4 + r] = rsum[r];
  }
  __syncthreads();
  float inv[4];
#pragma unroll
  for (int r = 0; r < 4; ++r) {
    int row = quad * 4 + r;
    float s = rs_lds[0][row] + rs_lds[1][row] + rs_lds[2][row] + rs_lds[3][row];
    inv[r] = 1.0f / s;
  }

  // --- out_value = acc_o * inv (C/D layout: row=quad*4+r, col=v=16w+m16) ---
#pragma unroll
  for (int r = 0; r < 4; ++r) {
    int row = quad * 4 + r;
    out_val[((size_t)(n * LL + l0 + row)) * DD + 16 * w + m16] = acc_o[r] * inv[r];
  }

  // --- pass B: recompute scores, normalize, store P (the big HBM write) ---
  for (int c = 0; c < SS / 64; ++c) {
    const int sc = c * 64;
    const int scol = sc + w * 16 + m16;
    const __bf16* krow = kbase + (size_t)scol * DD;
    bf16x8 b0 = *(const bf16x8*)(krow + quad * 8);
    bf16x8 b1 = *(const bf16x8*)(krow + 32 + quad * 8);
    f32x4 acc = {0.f, 0.f, 0.f, 0.f};
    acc = __builtin_amdgcn_mfma_f32_16x16x32_bf16(aq0, b0, acc, 0, 0, 0);
    acc = __builtin_amdgcn_mfma_f32_16x16x32_bf16(aq1, b1, acc, 0, 0, 0);
#pragma unroll
    for (int r = 0; r < 4; ++r) {
      int row = quad * 4 + r;
      size_t idx = mrow_base + (size_t)row * SS + scol;
      int mk = mask[idx];
      out_score[idx] = mk ? __expf(acc[r]) * inv[r] : 0.0f;
    }
  }
}

extern "C" void kernel_launch(void* const* d_in, const int* in_sizes, int n_in,
                              void* d_out, int out_size, void* d_ws, size_t ws_size,
                              hipStream_t stream) {
  const float* q = (const float*)d_in[0];
  const float* k = (const float*)d_in[1];
  const float* v = (const float*)d_in[2];
  const int* mask = (const int*)d_in[3];  // harness materializes bool as int32

  float* out_val = (float*)d_out;                       // [8,2048,64]
  float* out_score = out_val + (size_t)NB * LL * DD;    // [8,2048,2048]

  __bf16* Qb = (__bf16*)d_ws;                  // 2 MB
  __bf16* Kb = Qb + (size_t)NB * LL * DD;      // 2 MB
  __bf16* Vt = Kb + (size_t)NB * SS * DD;      // 2 MB (transposed [n][v][s])

  prep_norm<<<dim3((NB * LL * 2) / 4), dim3(256), 0, stream>>>(q, k, Qb, Kb);
  prep_vt<<<dim3(SS / 64, NB), dim3(256), 0, stream>>>(v, Vt);
  attn_main<<<dim3(LL / 16, NB), dim3(256), 0, stream>>>(Qb, Kb, Vt, mask, out_val, out_score);
}